// Round 2
// baseline (1458.809 us; speedup 1.0000x reference)
//
#include <hip/hip_runtime.h>
#include <hip/hip_bf16.h>
#include <math.h>

#define Bb 16
#define DIN 16
#define LL 4096
#define HH 256
#define NN2 32
#define NLAY 4
#define HN (HH*NN2)
#define CH2 64
#define NC2 (LL/CH2)   // 64 chunks

// ---------------- encoder: h[b,h,l] = sum_i x[b,i,l]*ew[i,h] + eb[h] ----------------
__global__ __launch_bounds__(256) void enc_kernel(const float* __restrict__ x,
    const float* __restrict__ ew, const float* __restrict__ eb,
    float* __restrict__ hbuf) {
  int blk = blockIdx.x;
  int tile = blk & 15;
  int h = (blk >> 4) & (HH - 1);
  int b = blk >> 12;
  int l = tile * 256 + threadIdx.x;
  const float* xb = x + (size_t)b * DIN * LL + l;
  float acc = eb[h];
  #pragma unroll
  for (int i = 0; i < DIN; ++i)
    acc = fmaf(xb[(size_t)i * LL], ew[i * HH + h], acc);
  hbuf[((size_t)(b * HH + h)) * LL + l] = acc;
}

// ---------------- per-layer SSM coefficients ----------------
// coef layout: [0,HN) w_re | [HN,2HN) w_im | [2HN,3HN) 2*Cc_re | [3HN,4HN) 2*Cc_im
__global__ __launch_bounds__(256) void coef_kernel(
    const float* __restrict__ log_dt, const float* __restrict__ Are,
    const float* __restrict__ Aim, const float* __restrict__ Cre,
    const float* __restrict__ Cim, float* __restrict__ coef) {
  int idx = blockIdx.x * 256 + threadIdx.x;
  if (idx >= HN) return;
  int h = idx >> 5;
  float dt = expf(log_dt[h]);
  float ar = -expf(Are[idx]);
  float ai = Aim[idx];
  float dre = ar * dt, dim = ai * dt;
  float er = expf(dre);
  float wr = er * cosf(dim);
  float wi = er * sinf(dim);
  float nr = wr - 1.f, ni = wi;
  float inv = 1.f / (ar * ar + ai * ai);
  float qr = (nr * ar + ni * ai) * inv;
  float qi = (ni * ar - nr * ai) * inv;
  float crv = Cre[idx], civ = Cim[idx];
  coef[idx]          = wr;
  coef[HN + idx]     = wi;
  coef[2 * HN + idx] = 2.f * (crv * qr - civ * qi);
  coef[3 * HN + idx] = 2.f * (crv * qi + civ * qr);
}

// ---------------- fused SSM: recurrence + skip + gelu ----------------
// 512 threads = 64 chunks x 8 lanes; each lane owns 4 of the 32 complex states.
__global__ __launch_bounds__(512, 8) void s4_kernel(
    const float* __restrict__ zg, const float* __restrict__ coef,
    const float* __restrict__ Dvec, float* __restrict__ gout) {
  __shared__ float z_lds[LL + NC2];   // padded: index l -> l + (l>>6)
  __shared__ float st[NC2 * 66];      // per chunk: 32 states x (re,im), stride 66
  int bh = blockIdx.x;
  int h = bh & (HH - 1);
  int t = threadIdx.x;
  const float* zrow = zg + (size_t)bh * LL;
  #pragma unroll
  for (int p = 0; p < 2; ++p) {
    int i4 = p * 512 + t;
    float4 v = ((const float4*)zrow)[i4];
    int l = i4 * 4;
    int base = l + (l >> 6);
    z_lds[base] = v.x; z_lds[base + 1] = v.y; z_lds[base + 2] = v.z; z_lds[base + 3] = v.w;
  }
  float Dh = Dvec[h];
  int c = t >> 3;       // chunk 0..63
  int sub = t & 7;      // 8 lanes per chunk, 4 states each
  float wr[4], wi[4], cr[4], ci[4];
  const float* cf = coef + h * NN2;
  #pragma unroll
  for (int k = 0; k < 4; ++k) {
    int n = sub * 4 + k;
    wr[k] = cf[n];
    wi[k] = cf[HN + n];
    cr[k] = cf[2 * HN + n];
    ci[k] = cf[3 * HN + n];
  }
  __syncthreads();
  int zb = c * 65;           // = c*CH2 + (c*CH2>>6)
  int sb = c * 66 + sub * 8; // state base in st
  // phase 1: chunk-local recurrence (zero init), final states only
  float sr[4] = {0.f, 0.f, 0.f, 0.f}, si[4] = {0.f, 0.f, 0.f, 0.f};
  for (int j = 0; j < CH2; ++j) {
    float zv = z_lds[zb + j];
    #pragma unroll
    for (int k = 0; k < 4; ++k) {
      float nr = fmaf(wr[k], sr[k], fmaf(-wi[k], si[k], zv));
      float ni = fmaf(wr[k], si[k], wi[k] * sr[k]);
      sr[k] = nr; si[k] = ni;
    }
  }
  #pragma unroll
  for (int k = 0; k < 4; ++k) {
    st[sb + 2 * k] = sr[k];
    st[sb + 2 * k + 1] = si[k];
  }
  // M = w^CH2 per state (6 squarings)
  float pr[4], pi[4];
  #pragma unroll
  for (int k = 0; k < 4; ++k) { pr[k] = wr[k]; pi[k] = wi[k]; }
  #pragma unroll
  for (int q = 0; q < 6; ++q) {
    #pragma unroll
    for (int k = 0; k < 4; ++k) {
      float t0 = pr[k] * pr[k] - pi[k] * pi[k];
      pi[k] = 2.f * pr[k] * pi[k];
      pr[k] = t0;
    }
  }
  __syncthreads();
  // Kogge-Stone inclusive scan over chunks: X_c += M^(d) * X_{c-d}
  float xr[4], xi[4];
  #pragma unroll
  for (int k = 0; k < 4; ++k) { xr[k] = sr[k]; xi[k] = si[k]; }
  for (int d = 1; d < NC2; d <<= 1) {
    float qr[4], qi[4];
    if (c >= d) {
      int nb = (c - d) * 66 + sub * 8;
      #pragma unroll
      for (int k = 0; k < 4; ++k) {
        qr[k] = st[nb + 2 * k];
        qi[k] = st[nb + 2 * k + 1];
      }
    }
    __syncthreads();
    if (c >= d) {
      #pragma unroll
      for (int k = 0; k < 4; ++k) {
        xr[k] = fmaf(pr[k], qr[k], fmaf(-pi[k], qi[k], xr[k]));
        xi[k] = fmaf(pr[k], qi[k], fmaf(pi[k], qr[k], xi[k]));
      }
    }
    #pragma unroll
    for (int k = 0; k < 4; ++k) {
      float t0 = pr[k] * pr[k] - pi[k] * pi[k];
      pi[k] = 2.f * pr[k] * pi[k];
      pr[k] = t0;
    }
    #pragma unroll
    for (int k = 0; k < 4; ++k) {
      st[sb + 2 * k] = xr[k];
      st[sb + 2 * k + 1] = xi[k];
    }
    __syncthreads();
  }
  // init state for this chunk = inclusive prefix of chunk c-1
  if (c == 0) {
    #pragma unroll
    for (int k = 0; k < 4; ++k) { sr[k] = 0.f; si[k] = 0.f; }
  } else {
    int nb = (c - 1) * 66 + sub * 8;
    #pragma unroll
    for (int k = 0; k < 4; ++k) {
      sr[k] = st[nb + 2 * k];
      si[k] = st[nb + 2 * k + 1];
    }
  }
  // phase 3: recurrence with correct init + output; write v = z*D + y in place
  for (int j = 0; j < CH2; ++j) {
    float zv = z_lds[zb + j];
    float y = 0.f;
    #pragma unroll
    for (int k = 0; k < 4; ++k) {
      float nr = fmaf(wr[k], sr[k], fmaf(-wi[k], si[k], zv));
      float ni = fmaf(wr[k], si[k], wi[k] * sr[k]);
      sr[k] = nr; si[k] = ni;
      y = fmaf(cr[k], nr, fmaf(-ci[k], ni, y));
    }
    y += __shfl_xor(y, 1);
    y += __shfl_xor(y, 2);
    y += __shfl_xor(y, 4);
    if (sub == 0) z_lds[zb + j] = fmaf(zv, Dh, y);
  }
  __syncthreads();
  // epilogue: gelu (sigmoid form), coalesced write
  float* grow = gout + (size_t)bh * LL;
  #pragma unroll
  for (int p = 0; p < 8; ++p) {
    int l = p * 512 + t;
    float v = z_lds[l + (l >> 6)];
    float u = 1.5957691216057308f * fmaf(0.044715f * v, v * v, v);
    grow[l] = v / (1.f + __expf(-u));
  }
}

// ---------------- matmul (256x256) + bias + residual + LayerNorm, L-tile 16 ----------------
__global__ __launch_bounds__(256, 4) void mm_ln_kernel(
    const float* __restrict__ g_buf, float* __restrict__ h_buf,
    const float* __restrict__ W, const float* __restrict__ bo,
    const float* __restrict__ lw, const float* __restrict__ lb) {
  __shared__ float gt[HH * 16];   // g tile [h][l], stride 16 (broadcast b128 reads)
  __shared__ float ot[HH * 17];   // residual / output tile, stride 17
  int blk = blockIdx.x;
  int b = blk >> 8;               // L/16 = 256 tiles per batch
  int l0 = (blk & 255) * 16;
  int t = threadIdx.x;
  const float* gb = g_buf + (size_t)b * HH * LL + l0;
  const float* hbp = h_buf + (size_t)b * HH * LL + l0;
  #pragma unroll
  for (int p = 0; p < 4; ++p) {
    int row = p * 64 + (t >> 2);
    int c4 = (t & 3) * 4;
    float4 v = *(const float4*)(gb + (size_t)row * LL + c4);
    *(float4*)(gt + row * 16 + c4) = v;
    float4 r = *(const float4*)(hbp + (size_t)row * LL + c4);
    float* dst = ot + row * 17 + c4;
    dst[0] = r.x; dst[1] = r.y; dst[2] = r.z; dst[3] = r.w;
  }
  __syncthreads();
  int dd = t & 63;   // d = dd + 64*r
  int lg = t >> 6;   // l = lg*4 + j
  float acc[4][4];
  #pragma unroll
  for (int r = 0; r < 4; ++r)
    #pragma unroll
    for (int j = 0; j < 4; ++j) acc[r][j] = 0.f;
  for (int hh = 0; hh < HH; ++hh) {
    float w0 = W[hh * HH + dd];
    float w1 = W[hh * HH + dd + 64];
    float w2 = W[hh * HH + dd + 128];
    float w3 = W[hh * HH + dd + 192];
    float4 gv = *(const float4*)(gt + hh * 16 + lg * 4);
    #pragma unroll
    for (int j = 0; j < 4; ++j) {
      float g = (j == 0) ? gv.x : (j == 1) ? gv.y : (j == 2) ? gv.z : gv.w;
      acc[0][j] = fmaf(w0, g, acc[0][j]);
      acc[1][j] = fmaf(w1, g, acc[1][j]);
      acc[2][j] = fmaf(w2, g, acc[2][j]);
      acc[3][j] = fmaf(w3, g, acc[3][j]);
    }
  }
  float bo4[4], lw4[4], lb4[4];
  #pragma unroll
  for (int r = 0; r < 4; ++r) {
    int d = dd + 64 * r;
    bo4[r] = bo[d]; lw4[r] = lw[d]; lb4[r] = lb[d];
  }
  float vv[4][4];
  #pragma unroll
  for (int r = 0; r < 4; ++r)
    #pragma unroll
    for (int j = 0; j < 4; ++j)
      vv[r][j] = acc[r][j] + bo4[r] + ot[(dd + 64 * r) * 17 + lg * 4 + j];
  // LN stats: wave-wide butterfly per column (wave lg owns columns lg*4..lg*4+3)
  float mean4[4], rstd4[4];
  #pragma unroll
  for (int j = 0; j < 4; ++j) {
    float s = vv[0][j] + vv[1][j] + vv[2][j] + vv[3][j];
    float q = fmaf(vv[0][j], vv[0][j], fmaf(vv[1][j], vv[1][j],
              fmaf(vv[2][j], vv[2][j], vv[3][j] * vv[3][j])));
    #pragma unroll
    for (int m = 1; m < 64; m <<= 1) {
      s += __shfl_xor(s, m);
      q += __shfl_xor(q, m);
    }
    float mu = s * (1.f / 256.f);
    float var = q * (1.f / 256.f) - mu * mu;
    mean4[j] = mu;
    rstd4[j] = rsqrtf(var + 1e-5f);
  }
  __syncthreads();  // everyone done reading ot
  #pragma unroll
  for (int r = 0; r < 4; ++r)
    #pragma unroll
    for (int j = 0; j < 4; ++j)
      ot[(dd + 64 * r) * 17 + lg * 4 + j] =
          (vv[r][j] - mean4[j]) * rstd4[j] * lw4[r] + lb4[r];
  __syncthreads();
  float* hw = h_buf + (size_t)b * HH * LL + l0;
  #pragma unroll
  for (int p = 0; p < 4; ++p) {
    int row = p * 64 + (t >> 2);
    int c4 = (t & 3) * 4;
    const float* src = ot + row * 17 + c4;
    float4 v;
    v.x = src[0]; v.y = src[1]; v.z = src[2]; v.w = src[3];
    *(float4*)(hw + (size_t)row * LL + c4) = v;
  }
}

// ---------------- decoder: out[b,d,l] = sum_h h[b,h,l]*dw[h,d] + db[d] ----------------
__global__ __launch_bounds__(256) void dec_kernel(
    const float* __restrict__ hbuf, const float* __restrict__ dw,
    const float* __restrict__ db, float* __restrict__ outp) {
  __shared__ float dwl[HH * DIN];
  int blk = blockIdx.x;
  int b = blk >> 4;
  int l0 = (blk & 15) * 256;
  int t = threadIdx.x;
  #pragma unroll
  for (int p = 0; p < 16; ++p) dwl[p * 256 + t] = dw[p * 256 + t];
  __syncthreads();
  float acc[DIN];
  #pragma unroll
  for (int d = 0; d < DIN; ++d) acc[d] = db[d];
  const float* hb = hbuf + (size_t)b * HH * LL + l0;
  for (int hh = 0; hh < HH; ++hh) {
    float v = hb[(size_t)hh * LL + t];
    #pragma unroll
    for (int d = 0; d < DIN; ++d)
      acc[d] = fmaf(v, dwl[hh * DIN + d], acc[d]);
  }
  float* ob = outp + (size_t)b * DIN * LL + l0;
  #pragma unroll
  for (int d = 0; d < DIN; ++d) ob[(size_t)d * LL + t] = acc[d];
}

extern "C" void kernel_launch(void* const* d_in, const int* in_sizes, int n_in,
                              void* d_out, int out_size, void* d_ws, size_t ws_size,
                              hipStream_t stream) {
  const float* x      = (const float*)d_in[0];
  const float* enc_w  = (const float*)d_in[1];
  const float* enc_b  = (const float*)d_in[2];
  const float* log_dt = (const float*)d_in[3];
  const float* A_re   = (const float*)d_in[4];
  const float* A_im   = (const float*)d_in[5];
  const float* C_re   = (const float*)d_in[6];
  const float* C_im   = (const float*)d_in[7];
  const float* Dv     = (const float*)d_in[8];
  const float* W_out  = (const float*)d_in[9];
  const float* b_out  = (const float*)d_in[10];
  const float* ln_w   = (const float*)d_in[11];
  const float* ln_b   = (const float*)d_in[12];
  const float* dec_w  = (const float*)d_in[13];
  const float* dec_b  = (const float*)d_in[14];
  float* out = (float*)d_out;

  float* h_buf = (float*)d_ws;
  float* g_buf = h_buf + (size_t)Bb * HH * LL;
  float* coef  = g_buf + (size_t)Bb * HH * LL;

  enc_kernel<<<Bb * HH * (LL / 256), 256, 0, stream>>>(x, enc_w, enc_b, h_buf);
  for (int i = 0; i < NLAY; ++i) {
    coef_kernel<<<HN / 256, 256, 0, stream>>>(log_dt + i * HH, A_re + i * HN,
                                              A_im + i * HN, C_re + i * HN,
                                              C_im + i * HN, coef);
    s4_kernel<<<Bb * HH, 512, 0, stream>>>(h_buf, coef, Dv + i * HH, g_buf);
    mm_ln_kernel<<<Bb * (LL / 16), 256, 0, stream>>>(
        g_buf, h_buf, W_out + (size_t)i * HH * HH, b_out + i * HH,
        ln_w + i * HH, ln_b + i * HH);
  }
  dec_kernel<<<Bb * (LL / 256), 256, 0, stream>>>(h_buf, dec_w, dec_b, out);
}

// Round 3
// 1118.584 us; speedup vs baseline: 1.3042x; 1.3042x over previous
//
#include <hip/hip_runtime.h>
#include <hip/hip_bf16.h>
#include <math.h>

#define Bb 16
#define DIN 16
#define LL 4096
#define HH 256
#define NN2 32
#define NLAY 4
#define HN (HH*NN2)
#define CH2 64
#define NC2 (LL/CH2)   // 64 chunks
#define BN 32          // mm l-tile

typedef __attribute__((ext_vector_type(8))) short short8;
typedef __attribute__((ext_vector_type(4))) float f32x4;

__device__ inline unsigned short f2bf(float f) {
  unsigned int x = __float_as_uint(f);
  unsigned int r = x + 0x7FFFu + ((x >> 16) & 1u);   // RNE
  return (unsigned short)(r >> 16);
}
__device__ inline float bf2f(unsigned short u) {
  return __uint_as_float(((unsigned int)u) << 16);
}
__device__ inline unsigned int packsplit(float v) {
  unsigned short hi = f2bf(v);
  unsigned short lo = f2bf(v - bf2f(hi));
  return (((unsigned int)hi) << 16) | lo;
}

// ---------------- encoder ----------------
__global__ __launch_bounds__(256) void enc_kernel(const float* __restrict__ x,
    const float* __restrict__ ew, const float* __restrict__ eb,
    float* __restrict__ hbuf) {
  int blk = blockIdx.x;
  int tile = blk & 15;
  int h = (blk >> 4) & (HH - 1);
  int b = blk >> 12;
  int l = tile * 256 + threadIdx.x;
  const float* xb = x + (size_t)b * DIN * LL + l;
  float acc = eb[h];
  #pragma unroll
  for (int i = 0; i < DIN; ++i)
    acc = fmaf(xb[(size_t)i * LL], ew[i * HH + h], acc);
  hbuf[((size_t)(b * HH + h)) * LL + l] = acc;
}

// ---------------- per-layer SSM coefficients ----------------
__global__ __launch_bounds__(256) void coef_kernel(
    const float* __restrict__ log_dt, const float* __restrict__ Are,
    const float* __restrict__ Aim, const float* __restrict__ Cre,
    const float* __restrict__ Cim, float* __restrict__ coef) {
  int idx = blockIdx.x * 256 + threadIdx.x;
  if (idx >= HN) return;
  int h = idx >> 5;
  float dt = expf(log_dt[h]);
  float ar = -expf(Are[idx]);
  float ai = Aim[idx];
  float dre = ar * dt, dim = ai * dt;
  float er = expf(dre);
  float wr = er * cosf(dim);
  float wi = er * sinf(dim);
  float nr = wr - 1.f, ni = wi;
  float inv = 1.f / (ar * ar + ai * ai);
  float qr = (nr * ar + ni * ai) * inv;
  float qi = (ni * ar - nr * ai) * inv;
  float crv = Cre[idx], civ = Cim[idx];
  coef[idx]          = wr;
  coef[HN + idx]     = wi;
  coef[2 * HN + idx] = 2.f * (crv * qr - civ * qi);
  coef[3 * HN + idx] = 2.f * (crv * qi + civ * qr);
}

// ---------------- W pack: Wp[d*256+h] = split(W[h][d]) ----------------
__global__ __launch_bounds__(256) void wpack_kernel(const float* __restrict__ W,
                                                    unsigned int* __restrict__ Wp) {
  int idx = blockIdx.x * 256 + threadIdx.x;  // idx = d*256 + h
  int d = idx >> 8, h = idx & 255;
  Wp[idx] = packsplit(W[h * HH + d]);
}

// ---------------- fused SSM: recurrence + skip + gelu -> packed bf16 split ----------------
__global__ __launch_bounds__(512, 8) void s4_kernel(
    const float* __restrict__ zg, const float* __restrict__ coef,
    const float* __restrict__ Dvec, unsigned int* __restrict__ gout) {
  __shared__ float z_lds[LL + NC2];   // padded: index l -> l + (l>>6)
  __shared__ float st[NC2 * 66];
  int bh = blockIdx.x;
  int h = bh & (HH - 1);
  int t = threadIdx.x;
  const float* zrow = zg + (size_t)bh * LL;
  #pragma unroll
  for (int p = 0; p < 2; ++p) {
    int i4 = p * 512 + t;
    float4 v = ((const float4*)zrow)[i4];
    int l = i4 * 4;
    int base = l + (l >> 6);
    z_lds[base] = v.x; z_lds[base + 1] = v.y; z_lds[base + 2] = v.z; z_lds[base + 3] = v.w;
  }
  float Dh = Dvec[h];
  int c = t >> 3;
  int sub = t & 7;
  float wr[4], wi[4], cr[4], ci[4];
  const float* cf = coef + h * NN2;
  #pragma unroll
  for (int k = 0; k < 4; ++k) {
    int n = sub * 4 + k;
    wr[k] = cf[n];
    wi[k] = cf[HN + n];
    cr[k] = cf[2 * HN + n];
    ci[k] = cf[3 * HN + n];
  }
  __syncthreads();
  int zb = c * 65;
  int sb = c * 66 + sub * 8;
  float sr[4] = {0.f, 0.f, 0.f, 0.f}, si[4] = {0.f, 0.f, 0.f, 0.f};
  for (int j = 0; j < CH2; ++j) {
    float zv = z_lds[zb + j];
    #pragma unroll
    for (int k = 0; k < 4; ++k) {
      float nr = fmaf(wr[k], sr[k], fmaf(-wi[k], si[k], zv));
      float ni = fmaf(wr[k], si[k], wi[k] * sr[k]);
      sr[k] = nr; si[k] = ni;
    }
  }
  #pragma unroll
  for (int k = 0; k < 4; ++k) {
    st[sb + 2 * k] = sr[k];
    st[sb + 2 * k + 1] = si[k];
  }
  float pr[4], pi[4];
  #pragma unroll
  for (int k = 0; k < 4; ++k) { pr[k] = wr[k]; pi[k] = wi[k]; }
  #pragma unroll
  for (int q = 0; q < 6; ++q) {
    #pragma unroll
    for (int k = 0; k < 4; ++k) {
      float t0 = pr[k] * pr[k] - pi[k] * pi[k];
      pi[k] = 2.f * pr[k] * pi[k];
      pr[k] = t0;
    }
  }
  __syncthreads();
  float xr[4], xi[4];
  #pragma unroll
  for (int k = 0; k < 4; ++k) { xr[k] = sr[k]; xi[k] = si[k]; }
  for (int d = 1; d < NC2; d <<= 1) {
    float qr[4], qi[4];
    if (c >= d) {
      int nb = (c - d) * 66 + sub * 8;
      #pragma unroll
      for (int k = 0; k < 4; ++k) {
        qr[k] = st[nb + 2 * k];
        qi[k] = st[nb + 2 * k + 1];
      }
    }
    __syncthreads();
    if (c >= d) {
      #pragma unroll
      for (int k = 0; k < 4; ++k) {
        xr[k] = fmaf(pr[k], qr[k], fmaf(-pi[k], qi[k], xr[k]));
        xi[k] = fmaf(pr[k], qi[k], fmaf(pi[k], qr[k], xi[k]));
      }
    }
    #pragma unroll
    for (int k = 0; k < 4; ++k) {
      float t0 = pr[k] * pr[k] - pi[k] * pi[k];
      pi[k] = 2.f * pr[k] * pi[k];
      pr[k] = t0;
    }
    #pragma unroll
    for (int k = 0; k < 4; ++k) {
      st[sb + 2 * k] = xr[k];
      st[sb + 2 * k + 1] = xi[k];
    }
    __syncthreads();
  }
  if (c == 0) {
    #pragma unroll
    for (int k = 0; k < 4; ++k) { sr[k] = 0.f; si[k] = 0.f; }
  } else {
    int nb = (c - 1) * 66 + sub * 8;
    #pragma unroll
    for (int k = 0; k < 4; ++k) {
      sr[k] = st[nb + 2 * k];
      si[k] = st[nb + 2 * k + 1];
    }
  }
  for (int j = 0; j < CH2; ++j) {
    float zv = z_lds[zb + j];
    float y = 0.f;
    #pragma unroll
    for (int k = 0; k < 4; ++k) {
      float nr = fmaf(wr[k], sr[k], fmaf(-wi[k], si[k], zv));
      float ni = fmaf(wr[k], si[k], wi[k] * sr[k]);
      sr[k] = nr; si[k] = ni;
      y = fmaf(cr[k], nr, fmaf(-ci[k], ni, y));
    }
    y += __shfl_xor(y, 1);
    y += __shfl_xor(y, 2);
    y += __shfl_xor(y, 4);
    if (sub == 0) z_lds[zb + j] = fmaf(zv, Dh, y);
  }
  __syncthreads();
  unsigned int* grow = gout + (size_t)bh * LL;
  #pragma unroll
  for (int p = 0; p < 8; ++p) {
    int l = p * 512 + t;
    float v = z_lds[l + (l >> 6)];
    float u = 1.5957691216057308f * fmaf(0.044715f * v, v * v, v);
    v = v / (1.f + __expf(-u));
    grow[l] = packsplit(v);
  }
}

// ---------------- MFMA matmul + bias + residual + LayerNorm ----------------
// out tile 256(d) x 32(l); 4 waves each own 64 d rows. bf16-split 3-pass MFMA.
__global__ __launch_bounds__(256, 4) void mm_mfma_ln_kernel(
    const unsigned int* __restrict__ gp, float* __restrict__ h_buf,
    const unsigned int* __restrict__ Wp, const float* __restrict__ bo,
    const float* __restrict__ lw, const float* __restrict__ lb) {
  __shared__ unsigned int gt[BN * HH];       // swizzled transposed [l][h] packed
  __shared__ float red_s[4][BN];
  __shared__ float red_q[4][BN];
  int blk = blockIdx.x;
  int b = blk >> 7;
  int l0 = (blk & 127) * BN;
  int t = threadIdx.x;
  const unsigned int* gbase = gp + (size_t)b * HH * LL + l0;
  // stage transposed with XOR swizzle on 16B groups
  #pragma unroll
  for (int p = 0; p < 4; ++p) {
    int hh = p * 64 + (t >> 2);
    int lq = (t & 3) * 8;
    const uint4* src = (const uint4*)(gbase + (size_t)hh * LL + lq);
    uint4 v0 = src[0];
    uint4 v1 = src[1];
    unsigned int vals[8] = {v0.x, v0.y, v0.z, v0.w, v1.x, v1.y, v1.z, v1.w};
    #pragma unroll
    for (int j = 0; j < 8; ++j) {
      int l = lq + j;
      int xm = (l & 7) ^ ((l >> 3) & 3);
      int g4 = (hh >> 2) ^ xm;
      gt[l * HH + g4 * 4 + (hh & 3)] = vals[j];
    }
  }
  __syncthreads();
  int wv = t >> 6, lane = t & 63;
  int row16 = lane & 15, kgrp = lane >> 4;   // kgrp 0..3
  f32x4 acc[4][2];
  #pragma unroll
  for (int di = 0; di < 4; ++di)
    #pragma unroll
    for (int li = 0; li < 2; ++li)
      acc[di][li] = (f32x4){0.f, 0.f, 0.f, 0.f};
  const unsigned int* wbase = Wp + (size_t)(wv * 64) * HH;
  #pragma unroll 2
  for (int ks = 0; ks < 8; ++ks) {
    int h0 = ks * 32;
    short8 Bhi[2], Blo[2];
    #pragma unroll
    for (int li = 0; li < 2; ++li) {
      int l = li * 16 + row16;
      int xm = (l & 7) ^ ((l >> 3) & 3);
      int g4a = ((h0 >> 2) + kgrp) ^ xm;
      int g4b = ((h0 >> 2) + kgrp + 4) ^ xm;
      uint4 pa = *(const uint4*)&gt[l * HH + g4a * 4];
      uint4 pb = *(const uint4*)&gt[l * HH + g4b * 4];
      union { int i[4]; short8 s; } uh, ul;
      uh.i[0] = (int)((pa.x >> 16) | (pa.y & 0xFFFF0000u));
      uh.i[1] = (int)((pa.z >> 16) | (pa.w & 0xFFFF0000u));
      uh.i[2] = (int)((pb.x >> 16) | (pb.y & 0xFFFF0000u));
      uh.i[3] = (int)((pb.z >> 16) | (pb.w & 0xFFFF0000u));
      ul.i[0] = (int)((pa.x & 0xFFFFu) | (pa.y << 16));
      ul.i[1] = (int)((pa.z & 0xFFFFu) | (pa.w << 16));
      ul.i[2] = (int)((pb.x & 0xFFFFu) | (pb.y << 16));
      ul.i[3] = (int)((pb.z & 0xFFFFu) | (pb.w << 16));
      Bhi[li] = uh.s; Blo[li] = ul.s;
    }
    #pragma unroll
    for (int di = 0; di < 4; ++di) {
      int d = di * 16 + row16;
      const unsigned int* wr = wbase + (size_t)d * HH + h0 + kgrp * 4;
      uint4 pa = *(const uint4*)wr;
      uint4 pb = *(const uint4*)(wr + 16);
      union { int i[4]; short8 s; } uh, ul;
      uh.i[0] = (int)((pa.x >> 16) | (pa.y & 0xFFFF0000u));
      uh.i[1] = (int)((pa.z >> 16) | (pa.w & 0xFFFF0000u));
      uh.i[2] = (int)((pb.x >> 16) | (pb.y & 0xFFFF0000u));
      uh.i[3] = (int)((pb.z >> 16) | (pb.w & 0xFFFF0000u));
      ul.i[0] = (int)((pa.x & 0xFFFFu) | (pa.y << 16));
      ul.i[1] = (int)((pa.z & 0xFFFFu) | (pa.w << 16));
      ul.i[2] = (int)((pb.x & 0xFFFFu) | (pb.y << 16));
      ul.i[3] = (int)((pb.z & 0xFFFFu) | (pb.w << 16));
      short8 Ahi = uh.s, Alo = ul.s;
      #pragma unroll
      for (int li = 0; li < 2; ++li) {
        acc[di][li] = __builtin_amdgcn_mfma_f32_16x16x32_bf16(Ahi, Bhi[li], acc[di][li], 0, 0, 0);
        acc[di][li] = __builtin_amdgcn_mfma_f32_16x16x32_bf16(Ahi, Blo[li], acc[di][li], 0, 0, 0);
        acc[di][li] = __builtin_amdgcn_mfma_f32_16x16x32_bf16(Alo, Bhi[li], acc[di][li], 0, 0, 0);
      }
    }
  }
  // bias + residual
  const float* hb = h_buf + (size_t)b * HH * LL + l0;
  #pragma unroll
  for (int di = 0; di < 4; ++di) {
    #pragma unroll
    for (int r = 0; r < 4; ++r) {
      int d = wv * 64 + di * 16 + kgrp * 4 + r;
      float bov = bo[d];
      #pragma unroll
      for (int li = 0; li < 2; ++li) {
        int l = li * 16 + row16;
        acc[di][li][r] += bov + hb[(size_t)d * LL + l];
      }
    }
  }
  // LN stats: per-column over this wave's 64 rows, then cross-wave via LDS
  #pragma unroll
  for (int li = 0; li < 2; ++li) {
    float s = 0.f, q = 0.f;
    #pragma unroll
    for (int di = 0; di < 4; ++di)
      #pragma unroll
      for (int r = 0; r < 4; ++r) {
        float v = acc[di][li][r];
        s += v;
        q = fmaf(v, v, q);
      }
    s += __shfl_xor(s, 16); s += __shfl_xor(s, 32);
    q += __shfl_xor(q, 16); q += __shfl_xor(q, 32);
    if (lane < 16) {
      red_s[wv][li * 16 + lane] = s;
      red_q[wv][li * 16 + lane] = q;
    }
  }
  __syncthreads();
  float mu[2], rstd[2];
  #pragma unroll
  for (int li = 0; li < 2; ++li) {
    int cl = li * 16 + row16;
    float s = red_s[0][cl] + red_s[1][cl] + red_s[2][cl] + red_s[3][cl];
    float q = red_q[0][cl] + red_q[1][cl] + red_q[2][cl] + red_q[3][cl];
    float m = s * (1.f / 256.f);
    float var = q * (1.f / 256.f) - m * m;
    mu[li] = m;
    rstd[li] = rsqrtf(var + 1e-5f);
  }
  float* hw = h_buf + (size_t)b * HH * LL + l0;
  #pragma unroll
  for (int di = 0; di < 4; ++di) {
    #pragma unroll
    for (int r = 0; r < 4; ++r) {
      int d = wv * 64 + di * 16 + kgrp * 4 + r;
      float lwv = lw[d], lbv = lb[d];
      #pragma unroll
      for (int li = 0; li < 2; ++li) {
        int l = li * 16 + row16;
        hw[(size_t)d * LL + l] = (acc[di][li][r] - mu[li]) * rstd[li] * lwv + lbv;
      }
    }
  }
}

// ---------------- decoder ----------------
__global__ __launch_bounds__(256) void dec_kernel(
    const float* __restrict__ hbuf, const float* __restrict__ dw,
    const float* __restrict__ db, float* __restrict__ outp) {
  __shared__ float dwl[HH * DIN];
  int blk = blockIdx.x;
  int b = blk >> 4;
  int l0 = (blk & 15) * 256;
  int t = threadIdx.x;
  #pragma unroll
  for (int p = 0; p < 16; ++p) dwl[p * 256 + t] = dw[p * 256 + t];
  __syncthreads();
  float acc[DIN];
  #pragma unroll
  for (int d = 0; d < DIN; ++d) acc[d] = db[d];
  const float* hb = hbuf + (size_t)b * HH * LL + l0;
  for (int hh = 0; hh < HH; ++hh) {
    float v = hb[(size_t)hh * LL + t];
    #pragma unroll
    for (int d = 0; d < DIN; ++d)
      acc[d] = fmaf(v, dwl[hh * DIN + d], acc[d]);
  }
  float* ob = outp + (size_t)b * DIN * LL + l0;
  #pragma unroll
  for (int d = 0; d < DIN; ++d) ob[(size_t)d * LL + t] = acc[d];
}

extern "C" void kernel_launch(void* const* d_in, const int* in_sizes, int n_in,
                              void* d_out, int out_size, void* d_ws, size_t ws_size,
                              hipStream_t stream) {
  const float* x      = (const float*)d_in[0];
  const float* enc_w  = (const float*)d_in[1];
  const float* enc_b  = (const float*)d_in[2];
  const float* log_dt = (const float*)d_in[3];
  const float* A_re   = (const float*)d_in[4];
  const float* A_im   = (const float*)d_in[5];
  const float* C_re   = (const float*)d_in[6];
  const float* C_im   = (const float*)d_in[7];
  const float* Dv     = (const float*)d_in[8];
  const float* W_out  = (const float*)d_in[9];
  const float* b_out  = (const float*)d_in[10];
  const float* ln_w   = (const float*)d_in[11];
  const float* ln_b   = (const float*)d_in[12];
  const float* dec_w  = (const float*)d_in[13];
  const float* dec_b  = (const float*)d_in[14];
  float* out = (float*)d_out;

  float* h_buf = (float*)d_ws;
  unsigned int* g_pack = (unsigned int*)(h_buf + (size_t)Bb * HH * LL);
  float* coef = (float*)(g_pack + (size_t)Bb * HH * LL);
  unsigned int* Wp = (unsigned int*)(coef + 4 * HN);

  enc_kernel<<<Bb * HH * (LL / 256), 256, 0, stream>>>(x, enc_w, enc_b, h_buf);
  for (int i = 0; i < NLAY; ++i) {
    coef_kernel<<<HN / 256, 256, 0, stream>>>(log_dt + i * HH, A_re + i * HN,
                                              A_im + i * HN, C_re + i * HN,
                                              C_im + i * HN, coef);
    wpack_kernel<<<HH * HH / 256, 256, 0, stream>>>(W_out + (size_t)i * HH * HH, Wp);
    s4_kernel<<<Bb * HH, 512, 0, stream>>>(h_buf, coef, Dv + i * HH, g_pack);
    mm_mfma_ln_kernel<<<Bb * (LL / BN), 256, 0, stream>>>(
        g_pack, h_buf, Wp, b_out + i * HH, ln_w + i * HH, ln_b + i * HH);
  }
  dec_kernel<<<Bb * (LL / 256), 256, 0, stream>>>(h_buf, dec_w, dec_b, out);
}